// Round 1
// baseline (58.623 us; speedup 1.0000x reference)
//
#include <hip/hip_runtime.h>
#include <math.h>

#define HIDDEN     256
#define NUM_GRAPHS 128
#define TABLE_N    4096          // table entries over s in [0, 16)
#define TABLE_M    16            // s-values (or nodes) per block in GEMM-style kernels
#define DS         (1.0f/256.0f)
#define INV_DS     256.0f
#define NB         32            // nodes per block in lerp kernel

// ---------------------------------------------------------------------------
// Kernel 1: per-graph center via binary search on sorted batch + block reduce.
// Deterministic (fixed reduction tree, no atomics). 128 blocks x 256 threads.
// ---------------------------------------------------------------------------
__global__ __launch_bounds__(256)
void graph_center_kernel(const float* __restrict__ pos,
                         const int*   __restrict__ batch,
                         int N, float* __restrict__ center) {
    int g = blockIdx.x;

    // lower_bound(g)
    int lo = 0, hi = N;
    while (lo < hi) { int mid = (lo + hi) >> 1; if (batch[mid] <  g) lo = mid + 1; else hi = mid; }
    int start = lo;
    // upper_bound(g)
    hi = N;
    while (lo < hi) { int mid = (lo + hi) >> 1; if (batch[mid] <= g) lo = mid + 1; else hi = mid; }
    int end = lo;

    float sx = 0.f, sy = 0.f, sz = 0.f;
    for (int n = start + threadIdx.x; n < end; n += blockDim.x) {
        sx += pos[n*3 + 0];
        sy += pos[n*3 + 1];
        sz += pos[n*3 + 2];
    }

    __shared__ float rx[256], ry[256], rz[256];
    int t = threadIdx.x;
    rx[t] = sx; ry[t] = sy; rz[t] = sz;
    __syncthreads();
    for (int off = 128; off > 0; off >>= 1) {
        if (t < off) { rx[t] += rx[t+off]; ry[t] += ry[t+off]; rz[t] += rz[t+off]; }
        __syncthreads();
    }
    if (t == 0) {
        float c   = (float)(end - start);
        float inv = (c > 0.f) ? (1.f / c) : 0.f;   // empty graph -> center 0 (matches ref where())
        center[g*3 + 0] = rx[0] * inv;
        center[g*3 + 1] = ry[0] * inv;
        center[g*3 + 2] = rz[0] * inv;
    }
}

// ---------------------------------------------------------------------------
// Kernel 2: build lookup table T[m][k] = b2[k] + sum_j silu(s_m*W1[j]+b1[j])*W2[j][k]
// s_m = m * DS. 256 blocks (TABLE_N/TABLE_M) x 256 threads.
// ---------------------------------------------------------------------------
__global__ __launch_bounds__(256)
void build_table_kernel(const float* __restrict__ W1,
                        const float* __restrict__ b1,
                        const float* __restrict__ W2,
                        const float* __restrict__ b2,
                        float* __restrict__ T) {
    __shared__ float H[TABLE_M][HIDDEN];
    int k  = threadIdx.x;          // 0..255 -> output column AND hidden index j=k for H
    int m0 = blockIdx.x * TABLE_M;

    float w1 = W1[k], B1 = b1[k];
    #pragma unroll
    for (int mi = 0; mi < TABLE_M; ++mi) {
        float s = (float)(m0 + mi) * DS;
        float x = fmaf(s, w1, B1);
        H[mi][k] = x / (1.f + __expf(-x));   // silu
    }
    __syncthreads();

    float acc[TABLE_M];
    float B2 = b2[k];
    #pragma unroll
    for (int mi = 0; mi < TABLE_M; ++mi) acc[mi] = B2;

    for (int j = 0; j < HIDDEN; ++j) {
        float w = W2[j*HIDDEN + k];          // coalesced across threads
        #pragma unroll
        for (int mi = 0; mi < TABLE_M; ++mi)
            acc[mi] = fmaf(H[mi][j], w, acc[mi]);   // H[mi][j]: LDS broadcast
    }
    #pragma unroll
    for (int mi = 0; mi < TABLE_M; ++mi)
        T[(size_t)(m0 + mi)*HIDDEN + k] = acc[mi];
}

// ---------------------------------------------------------------------------
// Kernel 3: per node, s = max(||pos - center[batch]||, eps); out row = lerp(T).
// ceil(N/NB) blocks x 256 threads.
// ---------------------------------------------------------------------------
__global__ __launch_bounds__(256)
void lerp_out_kernel(const float* __restrict__ pos,
                     const int*   __restrict__ batch,
                     const float* __restrict__ center,
                     const float* __restrict__ T,
                     float* __restrict__ out, int N) {
    __shared__ float tval[NB];
    int base = blockIdx.x * NB;
    int tid  = threadIdx.x;

    if (tid < NB) {
        int n = base + tid;
        float tv = 0.f;
        if (n < N) {
            int g = batch[n];
            float dx = pos[n*3 + 0] - center[g*3 + 0];
            float dy = pos[n*3 + 1] - center[g*3 + 1];
            float dz = pos[n*3 + 2] - center[g*3 + 2];
            float s  = sqrtf(fmaf(dx, dx, fmaf(dy, dy, dz*dz)));
            s  = fmaxf(s, 1e-8f);
            tv = s * INV_DS;
        }
        tval[tid] = tv;
    }
    __syncthreads();

    int k = tid;
    for (int mi = 0; mi < NB; ++mi) {
        int n = base + mi;
        if (n >= N) break;
        float t    = tval[mi];
        int   i    = (int)t;                 // t >= 0, trunc == floor
        i          = min(i, TABLE_N - 2);    // clamp (linear extrapolation beyond grid)
        float frac = t - (float)i;
        float a = T[(size_t)i*HIDDEN + k];
        float b = T[(size_t)(i+1)*HIDDEN + k];
        out[(size_t)n*HIDDEN + k] = fmaf(frac, b - a, a);
    }
}

// ---------------------------------------------------------------------------
// Fallback: direct per-node compute (if ws too small for the table).
// ---------------------------------------------------------------------------
__global__ __launch_bounds__(256)
void direct_kernel(const float* __restrict__ pos,
                   const int*   __restrict__ batch,
                   const float* __restrict__ center,
                   const float* __restrict__ W1,
                   const float* __restrict__ b1,
                   const float* __restrict__ W2,
                   const float* __restrict__ b2,
                   float* __restrict__ out, int N) {
    __shared__ float H[TABLE_M][HIDDEN];
    __shared__ float sv[TABLE_M];
    int k  = threadIdx.x;
    int n0 = blockIdx.x * TABLE_M;

    if (k < TABLE_M) {
        int n = n0 + k;
        float s = 0.f;
        if (n < N) {
            int g = batch[n];
            float dx = pos[n*3 + 0] - center[g*3 + 0];
            float dy = pos[n*3 + 1] - center[g*3 + 1];
            float dz = pos[n*3 + 2] - center[g*3 + 2];
            s = fmaxf(sqrtf(fmaf(dx, dx, fmaf(dy, dy, dz*dz))), 1e-8f);
        }
        sv[k] = s;
    }
    __syncthreads();

    float w1 = W1[k], B1 = b1[k];
    #pragma unroll
    for (int mi = 0; mi < TABLE_M; ++mi) {
        float x = fmaf(sv[mi], w1, B1);
        H[mi][k] = x / (1.f + __expf(-x));
    }
    __syncthreads();

    float acc[TABLE_M];
    float B2 = b2[k];
    #pragma unroll
    for (int mi = 0; mi < TABLE_M; ++mi) acc[mi] = B2;

    for (int j = 0; j < HIDDEN; ++j) {
        float w = W2[j*HIDDEN + k];
        #pragma unroll
        for (int mi = 0; mi < TABLE_M; ++mi)
            acc[mi] = fmaf(H[mi][j], w, acc[mi]);
    }
    #pragma unroll
    for (int mi = 0; mi < TABLE_M; ++mi) {
        int n = n0 + mi;
        if (n < N) out[(size_t)n*HIDDEN + k] = acc[mi];
    }
}

// ---------------------------------------------------------------------------
extern "C" void kernel_launch(void* const* d_in, const int* in_sizes, int n_in,
                              void* d_out, int out_size, void* d_ws, size_t ws_size,
                              hipStream_t stream) {
    // inputs: 0=node_feat (UNUSED), 1=node_pos [N,3], 2=batch [N] int32,
    //         3=W1 [1,256], 4=b1 [256], 5=W2 [256,256], 6=b2 [256]
    const float* node_pos = (const float*)d_in[1];
    const int*   batch    = (const int*)  d_in[2];
    const float* W1       = (const float*)d_in[3];
    const float* b1       = (const float*)d_in[4];
    const float* W2       = (const float*)d_in[5];
    const float* b2       = (const float*)d_in[6];
    float*       out      = (float*)d_out;

    int N = in_sizes[1] / 3;

    // ws layout: [0,1536) center[128][3]; [4096, 4096+4MB) table
    float* center = (float*)d_ws;
    float* T      = (float*)((char*)d_ws + 4096);
    size_t need   = 4096 + (size_t)TABLE_N * HIDDEN * sizeof(float);

    graph_center_kernel<<<NUM_GRAPHS, 256, 0, stream>>>(node_pos, batch, N, center);

    if (ws_size >= need) {
        build_table_kernel<<<TABLE_N / TABLE_M, HIDDEN, 0, stream>>>(W1, b1, W2, b2, T);
        lerp_out_kernel<<<(N + NB - 1) / NB, HIDDEN, 0, stream>>>(node_pos, batch, center, T, out, N);
    } else {
        direct_kernel<<<(N + TABLE_M - 1) / TABLE_M, HIDDEN, 0, stream>>>(
            node_pos, batch, center, W1, b1, W2, b2, out, N);
    }
}

// Round 2
// 57.247 us; speedup vs baseline: 1.0240x; 1.0240x over previous
//
#include <hip/hip_runtime.h>
#include <math.h>

#define HIDDEN   256
#define G_NUM    128
#define TN       1024            // table rows; s grid = [0,16) step 1/64
#define INV_DS   64.0f
#define DS       (1.0f/64.0f)
#define TM       4               // table rows per block
#define TBLOCKS  (TN/TM)         // 256 table blocks
#define SLICES   8               // blocks per graph in main kernel

__device__ inline float readlane_f(float v, int l) {
    union { float f; unsigned u; } a, r;
    a.f = v;
    r.u = __builtin_amdgcn_readlane(a.u, l);
    return r.f;
}

__device__ inline float silu(float x) {
    return x / (1.f + __expf(-x));
}

// ---------------------------------------------------------------------------
// Kernel A: blocks [0,TBLOCKS) build the lookup table
//             T[m][k] = b2[k] + sum_j silu(s_m*W1[j]+b1[j]) * W2[j][k]
//           using register-held H + v_readlane broadcast (no LDS in hot loop).
//           blocks [TBLOCKS, ...) compute per-graph segment bounds from the
//           sorted batch array via unique-writer boundary stores (no atomics,
//           no init needed -> deterministic, ws-poison-safe).
// ---------------------------------------------------------------------------
__global__ __launch_bounds__(256)
void table_bounds_kernel(const float* __restrict__ W1,
                         const float* __restrict__ b1v_,
                         const float* __restrict__ W2,
                         const float* __restrict__ b2v_,
                         const int*   __restrict__ batch,
                         int N,
                         int* __restrict__ bnd0, int* __restrict__ bnd1,
                         float* __restrict__ T) {
    int bid = blockIdx.x;
    if (bid < TBLOCKS) {
        int k  = threadIdx.x;          // output column (0..255)
        int l  = k & 63;               // lane
        int m0 = bid * TM;
        float s0 = (float)(m0 + 0) * DS;
        float s1 = (float)(m0 + 1) * DS;
        float s2 = (float)(m0 + 2) * DS;
        float s3 = (float)(m0 + 3) * DS;

        float acc0 = 0.f, acc1 = 0.f, acc2 = 0.f, acc3 = 0.f;

        for (int c = 0; c < HIDDEN / 64; ++c) {      // 4 chunks of 64 j
            int jb = c * 64;
            float w1 = W1[jb + l];
            float bb = b1v_[jb + l];
            // lane l holds H[mi][jb+l]
            float h0 = silu(fmaf(s0, w1, bb));
            float h1 = silu(fmaf(s1, w1, bb));
            float h2 = silu(fmaf(s2, w1, bb));
            float h3 = silu(fmaf(s3, w1, bb));
            const float* w2p = W2 + (size_t)jb * HIDDEN + k;
            #pragma unroll
            for (int jj = 0; jj < 64; ++jj) {
                float w2v = w2p[(size_t)jj * HIDDEN];   // coalesced dword
                acc0 = fmaf(readlane_f(h0, jj), w2v, acc0);
                acc1 = fmaf(readlane_f(h1, jj), w2v, acc1);
                acc2 = fmaf(readlane_f(h2, jj), w2v, acc2);
                acc3 = fmaf(readlane_f(h3, jj), w2v, acc3);
            }
        }
        float b2v = b2v_[k];
        T[(size_t)(m0 + 0) * HIDDEN + k] = acc0 + b2v;
        T[(size_t)(m0 + 1) * HIDDEN + k] = acc1 + b2v;
        T[(size_t)(m0 + 2) * HIDDEN + k] = acc2 + b2v;
        T[(size_t)(m0 + 3) * HIDDEN + k] = acc3 + b2v;
    } else {
        // segment bounds: bnd0[g] = first n with batch[n] >= g
        //                 bnd1[g] = first n with batch[n] >  g
        int n = (bid - TBLOCKS) * 256 + threadIdx.x;
        if (n < N) {
            int bn = batch[n];
            int bp = (n == 0) ? -1 : batch[n - 1];
            if (bn != bp) {
                for (int g = bp + 1; g <= bn; ++g) bnd0[g] = n;     // starts
                for (int g = (bp < 0 ? 0 : bp); g < bn; ++g) bnd1[g] = n; // ends of skipped/prev
            }
            if (n == N - 1) {
                for (int g = bn; g < G_NUM; ++g) bnd1[g] = N;
                for (int g = bn + 1; g < G_NUM; ++g) bnd0[g] = N;
            }
        }
    }
}

// ---------------------------------------------------------------------------
// Kernel B: fused center + output.
// Grid = G_NUM * SLICES. Each block: read bounds, block-reduce the graph's
// center (redundant but bitwise-identical across slices -> deterministic),
// then wave-per-node float4 lerp of the table into out.
// ---------------------------------------------------------------------------
__global__ __launch_bounds__(256)
void center_lerp_kernel(const float* __restrict__ pos,
                        const int*   __restrict__ bnd0,
                        const int*   __restrict__ bnd1,
                        const float* __restrict__ T,
                        float* __restrict__ out) {
    int g     = blockIdx.x >> 3;
    int slice = blockIdx.x & (SLICES - 1);
    int start = bnd0[g];
    int end   = bnd1[g];
    int cnt   = end - start;
    if (cnt <= 0) return;

    // ---- phase A: center of graph g (all 256 threads, fixed order) ----
    float sx = 0.f, sy = 0.f, sz = 0.f;
    for (int n = start + threadIdx.x; n < end; n += 256) {
        sx += pos[n * 3 + 0];
        sy += pos[n * 3 + 1];
        sz += pos[n * 3 + 2];
    }
    // wave butterfly reduce
    #pragma unroll
    for (int m = 32; m > 0; m >>= 1) {
        sx += __shfl_xor(sx, m, 64);
        sy += __shfl_xor(sy, m, 64);
        sz += __shfl_xor(sz, m, 64);
    }
    __shared__ float cw[3][4];
    __shared__ float ctr[3];
    int w    = threadIdx.x >> 6;
    int lane = threadIdx.x & 63;
    if (lane == 0) { cw[0][w] = sx; cw[1][w] = sy; cw[2][w] = sz; }
    __syncthreads();
    if (threadIdx.x == 0) {
        float inv = 1.f / (float)cnt;
        ctr[0] = (cw[0][0] + cw[0][1] + cw[0][2] + cw[0][3]) * inv;
        ctr[1] = (cw[1][0] + cw[1][1] + cw[1][2] + cw[1][3]) * inv;
        ctr[2] = (cw[2][0] + cw[2][1] + cw[2][2] + cw[2][3]) * inv;
    }
    __syncthreads();
    float cx = ctr[0], cy = ctr[1], cz = ctr[2];

    // ---- phase B: this slice's node range, one wave per node ----
    int ns = start + (int)(((long long)slice       * cnt) >> 3);
    int ne = start + (int)(((long long)(slice + 1) * cnt) >> 3);

    const float4* T4   = (const float4*)T;
    float4*       out4 = (float4*)out;

    for (int n = ns + w; n < ne; n += 4) {
        float dx = pos[n * 3 + 0] - cx;          // wave-uniform broadcast loads
        float dy = pos[n * 3 + 1] - cy;
        float dz = pos[n * 3 + 2] - cz;
        float s  = fmaxf(sqrtf(fmaf(dx, dx, fmaf(dy, dy, dz * dz))), 1e-8f);
        float t  = s * INV_DS;
        int   i  = (int)t;
        i = min(i, TN - 2);                      // clamp -> linear extrapolation
        float frac = t - (float)i;
        float4 a = T4[(size_t)i * (HIDDEN / 4) + lane];
        float4 b = T4[(size_t)(i + 1) * (HIDDEN / 4) + lane];
        float4 o;
        o.x = fmaf(frac, b.x - a.x, a.x);
        o.y = fmaf(frac, b.y - a.y, a.y);
        o.z = fmaf(frac, b.z - a.z, a.z);
        o.w = fmaf(frac, b.w - a.w, a.w);
        out4[(size_t)n * (HIDDEN / 4) + lane] = o;
    }
}

// ---------------------------------------------------------------------------
extern "C" void kernel_launch(void* const* d_in, const int* in_sizes, int n_in,
                              void* d_out, int out_size, void* d_ws, size_t ws_size,
                              hipStream_t stream) {
    // inputs: 0=node_feat (UNUSED), 1=node_pos [N,3], 2=batch [N] int32,
    //         3=W1 [1,256], 4=b1 [256], 5=W2 [256,256], 6=b2 [256]
    const float* node_pos = (const float*)d_in[1];
    const int*   batch    = (const int*)  d_in[2];
    const float* W1       = (const float*)d_in[3];
    const float* b1       = (const float*)d_in[4];
    const float* W2       = (const float*)d_in[5];
    const float* b2       = (const float*)d_in[6];
    float*       out      = (float*)d_out;

    int N = in_sizes[1] / 3;

    // ws layout: [0,512) bnd0[128]; [512,1024) bnd1[128]; [4096,..) T (1 MB)
    int*   bnd0 = (int*)d_ws;
    int*   bnd1 = (int*)((char*)d_ws + 512);
    float* T    = (float*)((char*)d_ws + 4096);

    int boundsBlocks = (N + 255) / 256;
    table_bounds_kernel<<<TBLOCKS + boundsBlocks, 256, 0, stream>>>(
        W1, b1, W2, b2, batch, N, bnd0, bnd1, T);

    center_lerp_kernel<<<G_NUM * SLICES, 256, 0, stream>>>(
        node_pos, bnd0, bnd1, T, out);
}